// Round 4
// baseline (212.149 us; speedup 1.0000x reference)
//
#include <hip/hip_runtime.h>
#include <hip/hip_bf16.h>

// Problem constants (fixed by reference setup_inputs)
#define M 4096
#define N 8192
#define D 128
#define TI 128
#define TJ 128
#define NITER 4     // i-tiles per block
#define LDB 136     // padded LDS stride (bf16 elems)

typedef __attribute__((ext_vector_type(8))) short short8_t;  // 8 bf16 (MFMA A/B frag)
typedef __attribute__((ext_vector_type(4))) float f32x4;     // MFMA C/D frag

__device__ inline short f2bf(float f) {
    union { float f; unsigned u; } v; v.f = f;
    unsigned r = v.u + 0x7FFFu + ((v.u >> 16) & 1u);
    return (short)(r >> 16);
}

// Kernel 0: squared row norms of sub_x (-> ws[0:M]) and all_x (-> ws[M:M+N]); zero d_out.
__global__ __launch_bounds__(256) void norms_kernel(const float* __restrict__ sub_x,
                                                    const float* __restrict__ all_x,
                                                    float* __restrict__ ws,
                                                    float* __restrict__ out) {
    int wave = threadIdx.x >> 6;
    int lane = threadIdx.x & 63;
    int row  = blockIdx.x * 4 + wave;   // 12288 rows = 3072 blocks * 4 waves

    const float* src;
    float* dst;
    if (row < M) { src = sub_x + (size_t)row * D; dst = ws + row; }
    else         { int r = row - M; src = all_x + (size_t)r * D; dst = ws + M + r; }

    float2 v = ((const float2*)src)[lane];
    float s = v.x * v.x + v.y * v.y;
    #pragma unroll
    for (int off = 32; off > 0; off >>= 1) s += __shfl_down(s, off, 64);
    if (lane == 0) dst[0] = s;

    if (blockIdx.x == 0 && threadIdx.x == 0) out[0] = 0.0f;
}

// Kernel 1 (R4): strip-streaming. Block = (tj, ig): stage all_x[tj] tile to LDS ONCE,
// then loop 4 i-tiles with NO barriers — waves free-run, loads overlap MFMA across waves.
// bid%8 = ig -> blocks sharing a sub_x strip land on the same XCD (L2 reuse).
__global__ __launch_bounds__(256, 2) void graph_loss_kernel(const float* __restrict__ G,
                                                            const float* __restrict__ sub_x,
                                                            const float* __restrict__ all_x,
                                                            const float* __restrict__ ws,
                                                            float* __restrict__ out) {
    __shared__ short Bs[TJ * LDB];
    __shared__ float red[4];

    const int tid  = threadIdx.x;
    const int lane = tid & 63;
    const int wave = tid >> 6;
    const int quad = lane >> 4;   // 0..3
    const int l16  = lane & 15;   // 0..15

    const int ig = blockIdx.x & 7;    // 0..7  (i-group; %8 -> XCD affinity for sub_x)
    const int tj = blockIdx.x >> 3;   // 0..63
    const int j0 = tj * TJ;

    const float* sxn = ws;        // [M]
    const float* axn = ws + M;    // [N]

    // ---- Stage all_x tile (128 rows x 128 k) -> LDS bf16, Bs[row][k]. ONCE per block. ----
    {
        const int tcol  = (tid & 31) * 4;
        const int trow0 = tid >> 5;
        #pragma unroll
        for (int r = 0; r < 16; ++r) {
            const int row = r * 8 + trow0;
            const float4 v = *(const float4*)(all_x + (size_t)(j0 + row) * D + tcol);
            short4 b;
            b.x = f2bf(v.x); b.y = f2bf(v.y); b.z = f2bf(v.z); b.w = f2bf(v.w);
            *(short4*)(&Bs[row * LDB + tcol]) = b;
        }
    }

    float ax[8];
    #pragma unroll
    for (int j = 0; j < 8; ++j)
        ax[j] = axn[j0 + j * 16 + l16];

    __syncthreads();   // the ONLY barrier before the final reduce

    float local = 0.0f;

    #pragma unroll 1   // keep rolled: gv+acc live ranges already ~200 VGPR
    for (int ii = 0; ii < NITER; ++ii) {
        const int i0 = (ig * NITER + ii) * TI;

        // -- G loads first (NT: single-use stream; don't pollute L2) --
        // C/D layout: elem r of lane -> row = quad*4 + r, col = lane&15
        float gv[2][4][8];
        float sx[2][4];
        #pragma unroll
        for (int s = 0; s < 2; ++s) {
            #pragma unroll
            for (int r = 0; r < 4; ++r) {
                const int row = i0 + (wave * 2 + s) * 16 + quad * 4 + r;
                const float* gp = G + (size_t)row * N + j0 + l16;
                #pragma unroll
                for (int j = 0; j < 8; ++j)
                    gv[s][r][j] = __builtin_nontemporal_load(gp + j * 16);
                sx[s][r] = sxn[row];
            }
        }

        // -- A fragments (sub_x, L2-resident per XCD) --
        // A-layout: lane holds A[m = lane&15][k = quad*8 + j], j=0..7
        short8_t a_frag[2][4];
        #pragma unroll
        for (int s = 0; s < 2; ++s) {
            const int m = i0 + (wave * 2 + s) * 16 + l16;
            const float* ap = sub_x + (size_t)m * D + quad * 8;
            #pragma unroll
            for (int t = 0; t < 4; ++t) {
                float4 v0 = *(const float4*)(ap + t * 32);
                float4 v1 = *(const float4*)(ap + t * 32 + 4);
                short8_t f;
                f[0] = f2bf(v0.x); f[1] = f2bf(v0.y); f[2] = f2bf(v0.z); f[3] = f2bf(v0.w);
                f[4] = f2bf(v1.x); f[5] = f2bf(v1.y); f[6] = f2bf(v1.z); f[7] = f2bf(v1.w);
                a_frag[s][t] = f;
            }
        }

        // -- MFMA: P = SX * AX^T over this 128x128 tile --
        f32x4 acc[2][8];
        #pragma unroll
        for (int s = 0; s < 2; ++s)
            #pragma unroll
            for (int j = 0; j < 8; ++j)
                acc[s][j] = (f32x4){0.f, 0.f, 0.f, 0.f};

        #pragma unroll
        for (int t = 0; t < 4; ++t) {
            short8_t b_frag[8];
            #pragma unroll
            for (int j = 0; j < 8; ++j)
                b_frag[j] = *(const short8_t*)(&Bs[(j * 16 + l16) * LDB + t * 32 + quad * 8]);
            #pragma unroll
            for (int s = 0; s < 2; ++s)
                #pragma unroll
                for (int j = 0; j < 8; ++j)
                    acc[s][j] = __builtin_amdgcn_mfma_f32_16x16x32_bf16(a_frag[s][t], b_frag[j],
                                                                        acc[s][j], 0, 0, 0);
        }

        // -- Combine with G (fp32, exact) --
        #pragma unroll
        for (int s = 0; s < 2; ++s) {
            #pragma unroll
            for (int r = 0; r < 4; ++r) {
                const float sv = sx[s][r];
                #pragma unroll
                for (int j = 0; j < 8; ++j)
                    local += gv[s][r][j] * (sv + ax[j] - 2.0f * acc[s][j][r]);
            }
        }
    }

    // ---- Reduce: wave shuffle -> LDS -> one atomic per block (pre-scaled; /2^25 exact) ----
    #pragma unroll
    for (int off = 32; off > 0; off >>= 1) local += __shfl_down(local, off, 64);
    if (lane == 0) red[wave] = local;
    __syncthreads();
    if (tid == 0) {
        const float bsum = red[0] + red[1] + red[2] + red[3];
        atomicAdd(out, bsum * (1.0f / 33554432.0f));   // / (m*n) = / 2^25
    }
}

extern "C" void kernel_launch(void* const* d_in, const int* in_sizes, int n_in,
                              void* d_out, int out_size, void* d_ws, size_t ws_size,
                              hipStream_t stream) {
    const float* G      = (const float*)d_in[0];  // [M,N]
    const float* sub_x  = (const float*)d_in[1];  // [M,D]
    const float* all_x  = (const float*)d_in[2];  // [N,D]
    float* out = (float*)d_out;
    float* ws  = (float*)d_ws;                    // sxn[M] | axn[N]  (48 KB)

    norms_kernel<<<(M + N) / 4, 256, 0, stream>>>(sub_x, all_x, ws, out);
    graph_loss_kernel<<<(N / TJ) * (M / TI / NITER), 256, 0, stream>>>(G, sub_x, all_x, ws, out);
}

// Round 5
// 203.545 us; speedup vs baseline: 1.0423x; 1.0423x over previous
//
#include <hip/hip_runtime.h>
#include <hip/hip_bf16.h>

// Problem constants (fixed by reference setup_inputs)
#define M 4096
#define N 8192
#define D 128

typedef __attribute__((ext_vector_type(8))) short short8_t;   // 8 bf16 (MFMA A/B frag, 4 VGPRs)
typedef __attribute__((ext_vector_type(16))) float f32x16;    // 32x32 MFMA C/D frag

__device__ inline unsigned short f2bf(float f) {
    union { float f; unsigned u; } v; v.f = f;
    unsigned r = v.u + 0x7FFFu + ((v.u >> 16) & 1u);
    return (unsigned short)(r >> 16);
}

// ws layout (floats):  sxn[M] | axn[N] | sxb_t (M*64 dwords) | axb_t (N*64 dwords)
// sxb_t/axb_t: bf16 x in k-major 16-B chunks: chunk (k8, row) = x[row][8*k8 .. 8*k8+7],
// stored at dword index (k8*R + row)*4 + q  (q = dword 0..3, elems 2q,2q+1; bf16[0] low bits).

// Kernel 0: row norms -> sxn/axn; bf16 k-major transposed copies -> sxb_t/axb_t; zero out.
__global__ __launch_bounds__(256) void prep_kernel(const float* __restrict__ sub_x,
                                                   const float* __restrict__ all_x,
                                                   float* __restrict__ ws,
                                                   float* __restrict__ out) {
    const int wave = threadIdx.x >> 6;
    const int lane = threadIdx.x & 63;
    const int row  = blockIdx.x * 4 + wave;   // 12288 rows = 3072 blocks * 4 waves

    unsigned* sxb = (unsigned*)(ws + M + N);
    unsigned* axb = sxb + (size_t)M * 64;

    const float* src; float* ndst; unsigned* tdst; int r, R;
    if (row < M) { r = row;     src = sub_x + (size_t)r * D; ndst = ws + r;     tdst = sxb; R = M; }
    else         { r = row - M; src = all_x + (size_t)r * D; ndst = ws + M + r; tdst = axb; R = N; }

    const float2 v = ((const float2*)src)[lane];   // elems 2*lane, 2*lane+1

    float s = v.x * v.x + v.y * v.y;
    #pragma unroll
    for (int off = 32; off > 0; off >>= 1) s += __shfl_down(s, off, 64);
    if (lane == 0) ndst[0] = s;

    const unsigned p = ((unsigned)f2bf(v.y) << 16) | (unsigned)f2bf(v.x);
    const int k8 = lane >> 2, q = lane & 3;
    tdst[((size_t)k8 * R + r) * 4 + q] = p;

    if (blockIdx.x == 0 && threadIdx.x == 0) out[0] = 0.0f;
}

// Kernel 1: block = 128x128 tile of G; wave w owns rows [w*32, w*32+32).
// 32x32x16 bf16 MFMA: C/D col = lane&31, row = (r&3)+8*(r>>2)+4*(lane>>5)  [verified m74/m101]
//                     A: lane holds A[m=lane&31][k=(lane>>5)*8+i];  B: B[k=(lane>>5)*8+i][n=lane&31]
// => each G load matched to C-layout reads 2 FULL 128-B cache lines (cols j0+jt*32+lane&31).
__global__ __launch_bounds__(256, 3) void graph_loss_kernel(const float* __restrict__ G,
                                                            const float* __restrict__ ws,
                                                            float* __restrict__ out) {
    __shared__ uint4 Bs[16 * 128];   // [k8][col] 16-B chunks, 32 KB
    __shared__ float red[4];

    const int tid  = threadIdx.x;
    const int lane = tid & 63;
    const int w    = tid >> 6;
    const int c    = lane & 31;   // col within 32-tile
    const int hw   = lane >> 5;   // half-wave -> k-offset / +4 rows

    const int ti = blockIdx.x >> 6;   // 0..31
    const int tj = blockIdx.x & 63;   // 0..63
    const int i0 = ti * 128;
    const int j0 = tj * 128;

    const float* sxn = ws;
    const float* axn = ws + M;
    const uint4* sxb = (const uint4*)(ws + M + N);        // [k8*M + m]
    const uint4* axb = sxb + (size_t)16 * M;              // [k8*N + j]

    // ---- Stage all_x-bf16 tile -> LDS (straight uint4 copy, coalesced, conflict-free) ----
    #pragma unroll
    for (int rr = 0; rr < 8; ++rr) {
        const int id  = rr * 256 + tid;     // 0..2047
        const int col = id & 127, k8 = id >> 7;
        Bs[id] = axb[(size_t)k8 * N + j0 + col];
    }

    // ---- A fragments: 8 k-steps, 16-B chunks, half-wave-coalesced ----
    short8_t a_frag[8];
    #pragma unroll
    for (int kk = 0; kk < 8; ++kk) {
        const uint4 t = sxb[(size_t)(kk * 2 + hw) * M + i0 + w * 32 + c];
        a_frag[kk] = *(const short8_t*)&t;
    }

    // ---- per-row norms for this wave's 32 rows (C-layout order) ----
    float sxv[16];
    #pragma unroll
    for (int r = 0; r < 16; ++r)
        sxv[r] = sxn[i0 + w * 32 + (r & 3) + 8 * (r >> 2) + 4 * hw];

    __syncthreads();   // only barrier before final reduce

    float local = 0.0f;

    #pragma unroll
    for (int jt = 0; jt < 4; ++jt) {
        // G loads first: 16 instrs, each 2 full 128-B lines; hidden behind the MFMA chain
        const float* gbase = G + (size_t)(i0 + w * 32 + 4 * hw) * N + j0 + jt * 32 + c;
        float gv[16];
        #pragma unroll
        for (int r = 0; r < 16; ++r)
            gv[r] = gbase[(size_t)((r & 3) + 8 * (r >> 2)) * N];

        const float axv = axn[j0 + jt * 32 + c];

        f32x16 acc;
        #pragma unroll
        for (int r = 0; r < 16; ++r) acc[r] = 0.0f;

        #pragma unroll
        for (int kk = 0; kk < 8; ++kk) {
            const short8_t b = *(const short8_t*)&Bs[(kk * 2 + hw) * 128 + jt * 32 + c];
            acc = __builtin_amdgcn_mfma_f32_32x32x16_bf16(a_frag[kk], b, acc, 0, 0, 0);
        }

        #pragma unroll
        for (int r = 0; r < 16; ++r)
            local += gv[r] * (sxv[r] + axv - 2.0f * acc[r]);
    }

    // ---- Reduce: wave shuffle -> LDS -> one atomic per block (pre-scaled; /2^25 exact) ----
    #pragma unroll
    for (int off = 32; off > 0; off >>= 1) local += __shfl_down(local, off, 64);
    if (lane == 0) red[w] = local;
    __syncthreads();
    if (tid == 0) {
        const float bsum = red[0] + red[1] + red[2] + red[3];
        atomicAdd(out, bsum * (1.0f / 33554432.0f));   // / (m*n) = / 2^25
    }
}

extern "C" void kernel_launch(void* const* d_in, const int* in_sizes, int n_in,
                              void* d_out, int out_size, void* d_ws, size_t ws_size,
                              hipStream_t stream) {
    const float* G      = (const float*)d_in[0];  // [M,N]
    const float* sub_x  = (const float*)d_in[1];  // [M,D]
    const float* all_x  = (const float*)d_in[2];  // [N,D]
    float* out = (float*)d_out;
    float* ws  = (float*)d_ws;                    // ~3.1 MB used

    prep_kernel<<<(M + N) / 4, 256, 0, stream>>>(sub_x, all_x, ws, out);
    graph_loss_kernel<<<(M / 128) * (N / 128), 256, 0, stream>>>(G, ws, out);
}

// Round 6
// 200.649 us; speedup vs baseline: 1.0573x; 1.0144x over previous
//
#include <hip/hip_runtime.h>
#include <hip/hip_bf16.h>

// Problem constants (fixed by reference setup_inputs)
#define M 4096
#define N 8192
#define D 128

typedef __attribute__((ext_vector_type(8))) short short8_t;   // 8 bf16 (MFMA A/B frag, 4 VGPRs)
typedef __attribute__((ext_vector_type(16))) float f32x16;    // 32x32 MFMA C/D frag

__device__ inline unsigned short f2bf(float f) {
    union { float f; unsigned u; } v; v.f = f;
    unsigned r = v.u + 0x7FFFu + ((v.u >> 16) & 1u);
    return (unsigned short)(r >> 16);
}

// ws layout (floats):  sxn[M] | axn[N] | sxb_t (M*64 dwords) | axb_t (N*64 dwords)
// sxb_t/axb_t: bf16 x in k-major 16-B chunks: chunk (k8, row) = x[row][8*k8 .. 8*k8+7].

// Kernel 0: row norms -> sxn/axn; bf16 k-major transposed copies -> sxb_t/axb_t; zero out.
__global__ __launch_bounds__(256) void prep_kernel(const float* __restrict__ sub_x,
                                                   const float* __restrict__ all_x,
                                                   float* __restrict__ ws,
                                                   float* __restrict__ out) {
    const int wave = threadIdx.x >> 6;
    const int lane = threadIdx.x & 63;
    const int row  = blockIdx.x * 4 + wave;   // 12288 rows = 3072 blocks * 4 waves

    unsigned* sxb = (unsigned*)(ws + M + N);
    unsigned* axb = sxb + (size_t)M * 64;

    const float* src; float* ndst; unsigned* tdst; int r, R;
    if (row < M) { r = row;     src = sub_x + (size_t)r * D; ndst = ws + r;     tdst = sxb; R = M; }
    else         { r = row - M; src = all_x + (size_t)r * D; ndst = ws + M + r; tdst = axb; R = N; }

    const float2 v = ((const float2*)src)[lane];   // elems 2*lane, 2*lane+1

    float s = v.x * v.x + v.y * v.y;
    #pragma unroll
    for (int off = 32; off > 0; off >>= 1) s += __shfl_down(s, off, 64);
    if (lane == 0) ndst[0] = s;

    const unsigned p = ((unsigned)f2bf(v.y) << 16) | (unsigned)f2bf(v.x);
    const int k8 = lane >> 2, q = lane & 3;
    tdst[((size_t)k8 * R + r) * 4 + q] = p;

    if (blockIdx.x == 0 && threadIdx.x == 0) out[0] = 0.0f;
}

// Kernel 1: block = 128x128 tile of G; wave w owns rows [w*32, w*32+32).
// 32x32x16 bf16 MFMA: C/D col = lane&31, row = (r&3)+8*(r>>2)+4*(lane>>5)  [verified, absmax 0]
// R6: double-buffered gv — prefetch jt+1's 16 full-line G loads before jt's MFMA chain,
// so every wave keeps >=16 loads in flight while computing (kills per-jt load->use stall).
__global__ __launch_bounds__(256, 3) void graph_loss_kernel(const float* __restrict__ G,
                                                            const float* __restrict__ ws,
                                                            float* __restrict__ out) {
    __shared__ uint4 Bs[16 * 128];   // [k8][col] 16-B chunks, 32 KB
    __shared__ float red[4];

    const int tid  = threadIdx.x;
    const int lane = tid & 63;
    const int w    = tid >> 6;
    const int c    = lane & 31;   // col within 32-tile
    const int hw   = lane >> 5;   // half-wave -> k-offset / +4 rows

    const int ti = blockIdx.x >> 6;   // 0..31
    const int tj = blockIdx.x & 63;   // 0..63
    const int i0 = ti * 128;
    const int j0 = tj * 128;

    const float* sxn = ws;
    const float* axn = ws + M;
    const uint4* sxb = (const uint4*)(ws + M + N);        // [k8*M + m]
    const uint4* axb = sxb + (size_t)16 * M;              // [k8*N + j]

    // ---- Stage all_x-bf16 tile -> LDS (straight uint4 copy, coalesced, conflict-free) ----
    #pragma unroll
    for (int rr = 0; rr < 8; ++rr) {
        const int id  = rr * 256 + tid;     // 0..2047
        const int col = id & 127, k8 = id >> 7;
        Bs[id] = axb[(size_t)k8 * N + j0 + col];
    }

    // ---- A fragments: 8 k-steps, 16-B chunks, half-wave-coalesced ----
    short8_t a_frag[8];
    #pragma unroll
    for (int kk = 0; kk < 8; ++kk) {
        const uint4 t = sxb[(size_t)(kk * 2 + hw) * M + i0 + w * 32 + c];
        a_frag[kk] = *(const short8_t*)&t;
    }

    // ---- per-row norms for this wave's 32 rows (C-layout order) ----
    float sxv[16];
    #pragma unroll
    for (int r = 0; r < 16; ++r)
        sxv[r] = sxn[i0 + w * 32 + (r & 3) + 8 * (r >> 2) + 4 * hw];

    float axv[4];
    #pragma unroll
    for (int jt = 0; jt < 4; ++jt)
        axv[jt] = axn[j0 + jt * 32 + c];

    const float* gbase = G + (size_t)(i0 + w * 32 + 4 * hw) * N + j0 + c;

    // ---- Prologue: gv for jt=0 ----
    float gv[2][16];
    #pragma unroll
    for (int r = 0; r < 16; ++r)
        gv[0][r] = gbase[(size_t)((r & 3) + 8 * (r >> 2)) * N];

    __syncthreads();   // only barrier before final reduce

    float local = 0.0f;

    #pragma unroll
    for (int jt = 0; jt < 4; ++jt) {
        // prefetch next jt's G tile-slice while this one computes
        if (jt < 3) {
            #pragma unroll
            for (int r = 0; r < 16; ++r)
                gv[(jt + 1) & 1][r] = gbase[(size_t)((r & 3) + 8 * (r >> 2)) * N + (jt + 1) * 32];
        }

        f32x16 acc;
        #pragma unroll
        for (int r = 0; r < 16; ++r) acc[r] = 0.0f;

        #pragma unroll
        for (int kk = 0; kk < 8; ++kk) {
            const short8_t b = *(const short8_t*)&Bs[(kk * 2 + hw) * 128 + jt * 32 + c];
            acc = __builtin_amdgcn_mfma_f32_32x32x16_bf16(a_frag[kk], b, acc, 0, 0, 0);
        }

        const float av = axv[jt];
        #pragma unroll
        for (int r = 0; r < 16; ++r)
            local += gv[jt & 1][r] * (sxv[r] + av - 2.0f * acc[r]);
    }

    // ---- Reduce: wave shuffle -> LDS -> one atomic per block (pre-scaled; /2^25 exact) ----
    #pragma unroll
    for (int off = 32; off > 0; off >>= 1) local += __shfl_down(local, off, 64);
    if (lane == 0) red[w] = local;
    __syncthreads();
    if (tid == 0) {
        const float bsum = red[0] + red[1] + red[2] + red[3];
        atomicAdd(out, bsum * (1.0f / 33554432.0f));   // / (m*n) = / 2^25
    }
}

extern "C" void kernel_launch(void* const* d_in, const int* in_sizes, int n_in,
                              void* d_out, int out_size, void* d_ws, size_t ws_size,
                              hipStream_t stream) {
    const float* G      = (const float*)d_in[0];  // [M,N]
    const float* sub_x  = (const float*)d_in[1];  // [M,D]
    const float* all_x  = (const float*)d_in[2];  // [N,D]
    float* out = (float*)d_out;
    float* ws  = (float*)d_ws;                    // ~3.1 MB used

    prep_kernel<<<(M + N) / 4, 256, 0, stream>>>(sub_x, all_x, ws, out);
    graph_loss_kernel<<<(M / 128) * (N / 128), 256, 0, stream>>>(G, ws, out);
}